// Round 3
// baseline (76.498 us; speedup 1.0000x reference)
//
#include <hip/hip_runtime.h>

#define H  544
#define W  960
#define T  8
#define R  4
#define HB (H / T)    // 68
#define WB (W / T)    // 120
#define NB (HB * WB)  // 8160
#define NC 81         // (2R+1)^2
#define WIN 16        // T + 2R

__device__ __forceinline__ int iclamp(int v, int lo, int hi) {
    return v < lo ? lo : (v > hi ? hi : v);
}

// ---- compile-time spiral table: rank (0-based) -> cell packed (wy<<4)|wx ----
struct SpiralTab { int v[NC]; };

__host__ __device__ constexpr SpiralTab make_spiral() {
    SpiralTab t{};
    int n = 0;
    for (int dy = 0; dy <= R; ++dy) {
        for (int dir = 0; dir < 4; ++dir) {
            int limit = (dir == 0 && dy == 0) ? 1 : dy;
            for (int dx = -dy; dx < limit; ++dx) {
                int wx, wy;
                if (dir == 0)      { wx = R + dx; wy = R + dy; }
                else if (dir == 1) { wx = R + dy; wy = R - dx; }
                else if (dir == 2) { wx = R - dx; wy = R - dy; }
                else               { wx = R - dy; wy = R + dx; }
                t.v[n] = (wy << 4) | wx;
                ++n;
            }
        }
    }
    return t;
}

static __constant__ SpiralTab SPIR = make_spiral();

// ---- packed-byte helpers ----
__device__ __forceinline__ unsigned int sadu8(unsigned int a, unsigned int b, unsigned int acc) {
#if __has_builtin(__builtin_amdgcn_sad_u8)
    return __builtin_amdgcn_sad_u8(a, b, acc);
#else
    unsigned int d;
    asm("v_sad_u8 %0, %1, %2, %3" : "=v"(d) : "v"(a), "v"(b), "v"(acc));
    return d;
#endif
}

__device__ __forceinline__ unsigned int alignb(unsigned int hi, unsigned int lo, unsigned int sh) {
#if __has_builtin(__builtin_amdgcn_alignbyte)
    return __builtin_amdgcn_alignbyte(hi, lo, sh);
#else
    unsigned int d;
    asm("v_alignbyte_b32 %0, %1, %2, %3" : "=v"(d) : "v"(hi), "v"(lo), "v"(sh));
    return d;
#endif
}

// Exact fp32 association ((a + 2*b) + c)*0.25, no FMA contraction.
#define VERT(a, b, c) (__fmul_rn(__fadd_rn(__fadd_rn((a), __fmul_rn(2.0f, (b))), (c)), 0.25f))
#define QU(h) ((unsigned int)fminf(fmaxf(rintf(__fmul_rn((h), 255.0f)), 0.0f), 255.0f))

// ============ KA: fused blur + 81-candidate SAD + spiral argmin ============
// One wave per 8x8 block; the wave recomputes the binomial blur for its own
// 16x16 prev region and 8x8 cur template (separable, in LDS), quantizes to
// bytes, then does packed-SAD. Also writes the block's owned 8x8 footprint of
// prev_q / cur_q / cur_blur for the downstream flow kernel.
__global__ void __launch_bounds__(256)
k_blur_sad(const float* __restrict__ cur, const float* __restrict__ prev,
           float* __restrict__ cur_blur,
           unsigned char* __restrict__ cur_q,
           unsigned char* __restrict__ prev_q,
           float* __restrict__ vecy, float* __restrict__ vecx) {
    __shared__ float vb[4][WIN][20];   // vertical blur of prev, cols bx0-5..bx0+12 (18 used)
    __shared__ float vc[4][T][12];     // vertical blur of cur,  cols bx0-1..bx0+8  (10 used)
    __shared__ uint4 region[4][WIN];   // 16 rows x 16 B quantized prev bytes
    __shared__ uint2 tmplS[4][T];      // 8 rows x 8 B quantized cur bytes

    int w    = threadIdx.x >> 6;
    int lane = threadIdx.x & 63;
    int bidx = blockIdx.x * 4 + w;     // NB = 2040*4, exact
    int byi = bidx / WB, bxi = bidx % WB;
    int by0 = byi * T, bx0 = bxi * T;

    // vertical pass, prev: 16 rows x 18 cols (cols clamp(bx0-5+cx))
    for (int e = lane; e < WIN * 18; e += 64) {
        int ry = e / 18, cx = e - ry * 18;
        int gy = iclamp(by0 - R + ry, 0, H - 1);
        int gx = iclamp(bx0 - 5 + cx, 0, W - 1);
        int ym = iclamp(gy - 1, 0, H - 1) * W;
        int yp = iclamp(gy + 1, 0, H - 1) * W;
        vb[w][ry][cx] = VERT(prev[ym + gx], prev[gy * W + gx], prev[yp + gx]);
    }
    // vertical pass, cur: 8 rows x 10 cols (cols clamp(bx0-1+cx))
    for (int e = lane; e < T * 10; e += 64) {
        int ty = e / 10, cx = e - ty * 10;
        int gy = by0 + ty;
        int gx = iclamp(bx0 - 1 + cx, 0, W - 1);
        int ym = iclamp(gy - 1, 0, H - 1) * W;
        int yp = iclamp(gy + 1, 0, H - 1) * W;
        vc[w][ty][cx] = VERT(cur[ym + gx], cur[gy * W + gx], cur[yp + gx]);
    }
    __syncthreads();

    // horizontal + quantize, prev 16x16 region; write owned center 8x8 to prev_q
    {
        unsigned char* regB = (unsigned char*)&region[w][0];
        int base = bx0 - 5;
        for (int e = lane; e < WIN * WIN; e += 64) {
            int ry = e >> 4, rx = e & 15;
            int gxp = iclamp(bx0 - R + rx, 0, W - 1);
            int xm = (gxp > 0) ? gxp - 1 : 0;
            int xp = (gxp < W - 1) ? gxp + 1 : W - 1;
            float h = VERT(vb[w][ry][xm - base], vb[w][ry][gxp - base], vb[w][ry][xp - base]);
            unsigned char b = (unsigned char)QU(h);
            regB[ry * 16 + rx] = b;
            if (ry >= R && ry < R + T && rx >= R && rx < R + T)
                prev_q[(by0 + ry - R) * W + (bx0 + rx - R)] = b;
        }
    }
    // horizontal + quantize, cur 8x8 template; write cur_q and cur_blur
    {
        int ty = lane >> 3, tx = lane & 7;
        float h = VERT(vc[w][ty][tx], vc[w][ty][tx + 1], vc[w][ty][tx + 2]);
        unsigned char b = (unsigned char)QU(h);
        ((unsigned char*)&tmplS[w][0])[ty * 8 + tx] = b;
        cur_q[(by0 + ty) * W + bx0 + tx] = b;
        cur_blur[(by0 + ty) * W + bx0 + tx] = h;
    }
    __syncthreads();

    unsigned int t0[T], t1[T];
#pragma unroll
    for (int ty = 0; ty < T; ++ty) {
        uint2 tt = tmplS[w][ty];
        t0[ty] = tt.x;
        t1[ty] = tt.y;
    }

    // candidate SAD for spiral ranks lane and lane+64
    int cell0 = SPIR.v[lane];
    int dy0 = cell0 >> 4, dx0 = cell0 & 15;
    bool v1 = (lane + 64) < NC;
    int cell1 = SPIR.v[v1 ? (lane + 64) : 0];
    int dy1 = cell1 >> 4, dx1 = cell1 & 15;

    unsigned int sad0 = 0, sad1 = 0;
    int q0 = dx0 >> 2; unsigned int r0 = (unsigned int)(dx0 & 3);
    int q1 = dx1 >> 2; unsigned int r1 = (unsigned int)(dx1 & 3);
#pragma unroll
    for (int ty = 0; ty < T; ++ty) {
        {
            uint4 row = region[w][ty + dy0];
            unsigned int w0 = (q0 == 0) ? row.x : ((q0 == 1) ? row.y : row.z);
            unsigned int w1 = (q0 == 0) ? row.y : ((q0 == 1) ? row.z : row.w);
            unsigned int w2 = (q0 == 0) ? row.z : row.w;
            sad0 = sadu8(alignb(w1, w0, r0), t0[ty], sad0);
            sad0 = sadu8(alignb(w2, w1, r0), t1[ty], sad0);
        }
        if (v1) {
            uint4 row = region[w][ty + dy1];
            unsigned int w0 = (q1 == 0) ? row.x : ((q1 == 1) ? row.y : row.z);
            unsigned int w1 = (q1 == 0) ? row.y : ((q1 == 1) ? row.z : row.w);
            unsigned int w2 = (q1 == 0) ? row.z : row.w;
            sad1 = sadu8(alignb(w1, w0, r1), t0[ty], sad1);
            sad1 = sadu8(alignb(w2, w1, r1), t1[ty], sad1);
        }
    }

    // key = (sad<<7) | rank — lanes are spiral-rank-ordered, so min key is
    // (min sad, earliest spiral).
    int key = (int)((sad0 << 7) | (unsigned int)lane);
    if (v1) {
        int k1 = (int)((sad1 << 7) | (unsigned int)(lane + 64));
        key = min(key, k1);
    }
#pragma unroll
    for (int off = 32; off > 0; off >>= 1)
        key = min(key, __shfl_xor(key, off));
    if (lane == 0) {
        int rank = key & 127;
        int cell = SPIR.v[rank];
        int dyi = (cell >> 4) - R;
        int dxi = (cell & 15) - R;
        vecy[bidx] = (float)(-dyi);
        vecx[bidx] = (float)(-dxi);
    }
}

// ============ KB: median + LK, 32 lanes per block ============
__device__ __forceinline__ void msort(float& a, float& b) {
    float mn = fminf(a, b), mx = fmaxf(a, b);
    a = mn; b = mx;
}

__device__ __forceinline__ float median9(float p[9]) {
    msort(p[1], p[2]); msort(p[4], p[5]); msort(p[7], p[8]);
    msort(p[0], p[1]); msort(p[3], p[4]); msort(p[6], p[7]);
    msort(p[1], p[2]); msort(p[4], p[5]); msort(p[7], p[8]);
    msort(p[0], p[3]); msort(p[5], p[8]); msort(p[4], p[7]);
    msort(p[3], p[6]); msort(p[1], p[4]); msort(p[2], p[5]);
    msort(p[4], p[7]); msort(p[4], p[2]); msort(p[6], p[4]);
    msort(p[4], p[2]);
    return p[4];
}

__global__ void __launch_bounds__(256)
k_flow(const unsigned char* __restrict__ cur_q,
       const unsigned char* __restrict__ prev_q,
       const float* __restrict__ cur_blur,
       const float* __restrict__ vecy, const float* __restrict__ vecx,
       float* __restrict__ out) {
    int bidx = blockIdx.x * 8 + (threadIdx.x >> 5);   // NB = 1020*8, exact
    int lane = threadIdx.x & 31;
    int byi = bidx / WB, bxi = bidx % WB;

    // 3x3 median (computed redundantly on all 32 lanes — uniform, no divergence)
    float py[9], px[9];
#pragma unroll
    for (int i = 0; i < 3; ++i)
#pragma unroll
        for (int j = 0; j < 3; ++j) {
            int yy = iclamp(byi + i - 1, 0, HB - 1);
            int xx = iclamp(bxi + j - 1, 0, WB - 1);
            py[i * 3 + j] = vecy[yy * WB + xx];
            px[i * 3 + j] = vecx[yy * WB + xx];
        }
    float vmy = median9(py);
    float vmx = median9(px);

    int med_y = iclamp((int)rintf(vmy), -R, R);
    int med_x = iclamp((int)rintf(vmx), -R, R);
    int off_y = -med_y, off_x = -med_x;   // vec stores negated offsets

    // border-ring pixel for this lane (28 active lanes)
    bool act = lane < 28;
    int k = act ? lane : 0;
    int ty, tx;
    if (k < 8)       { ty = 0;      tx = k;      }
    else if (k < 16) { ty = T - 1;  tx = k - 8;  }
    else if (k < 22) { ty = k - 15; tx = 0;      }
    else             { ty = k - 21; tx = T - 1;  }

    int by0 = byi * T, bx0 = bxi * T;
    int y = by0 + ty, x = bx0 + tx;
    float tmplv = (float)cur_q[y * W + x] / 255.0f;
    int my = iclamp(y + off_y, 0, H - 1);
    int mx = iclamp(x + off_x, 0, W - 1);
    float matv = (float)prev_q[my * W + mx] / 255.0f;
    float gyv = (cur_blur[iclamp(y + 1, 0, H - 1) * W + x]
               - cur_blur[iclamp(y - 1, 0, H - 1) * W + x]) * 0.5f;
    float gxv = (cur_blur[y * W + iclamp(x + 1, 0, W - 1)]
               - cur_blur[y * W + iclamp(x - 1, 0, W - 1)]) * 0.5f;
    float diff = matv - tmplv;

    float a = act ? gxv * gxv : 0.0f;
    float b = act ? gxv * gyv : 0.0f;
    float d = act ? gyv * gyv : 0.0f;
    float p = act ? diff * gxv : 0.0f;
    float q = act ? diff * gyv : 0.0f;
#pragma unroll
    for (int off = 16; off > 0; off >>= 1) {
        a += __shfl_xor(a, off);
        b += __shfl_xor(b, off);
        d += __shfl_xor(d, off);
        p += __shfl_xor(p, off);
        q += __shfl_xor(q, off);
    }

    if (lane == 0) {
        float det  = a * d - b * b;
        float safe = (det <= 1e-6f) ? 1.0f : det;
        float su = (d * p - b * q) / safe;
        float sv = (a * q - b * p) / safe;
        bool inval = (det <= 1e-6f);
        float sy = (inval || fabsf(sv) >= 1.0f) ? 0.0f : sv;
        float sx = (inval || fabsf(su) >= 1.0f) ? 0.0f : su;
        out[bidx]      = vmy + sy;
        out[NB + bidx] = vmx + sx;
    }
}

extern "C" void kernel_launch(void* const* d_in, const int* in_sizes, int n_in,
                              void* d_out, int out_size, void* d_ws, size_t ws_size,
                              hipStream_t stream) {
    const float* cur  = (const float*)d_in[0];
    const float* prev = (const float*)d_in[1];
    float* out = (float*)d_out;

    char* ws = (char*)d_ws;
    float*         cur_blur = (float*)ws;                               // H*W f32
    unsigned char* cur_q    = (unsigned char*)(ws + (size_t)H * W * 4); // H*W u8
    unsigned char* prev_q   = cur_q + (size_t)H * W;                    // H*W u8
    float*         vecy     = (float*)(ws + (size_t)H * W * 6);         // NB f32
    float*         vecx     = vecy + NB;                                // NB f32

    k_blur_sad<<<NB / 4, 256, 0, stream>>>(cur, prev, cur_blur, cur_q, prev_q, vecy, vecx);
    k_flow<<<NB / 8, 256, 0, stream>>>(cur_q, prev_q, cur_blur, vecy, vecx, out);
}